// Round 5
// baseline (447.860 us; speedup 1.0000x reference)
//
#include <hip/hip_runtime.h>

#define N 8192
#define D 128

typedef __attribute__((ext_vector_type(8))) short short8;   // 8 bf16 = 4 VGPRs
typedef __attribute__((ext_vector_type(4))) float float4v;  // MFMA C/D

__device__ __forceinline__ unsigned short f32_to_bf16(float f) {
    unsigned int u = __float_as_uint(f);
    unsigned int r = (u + 0x7fffu + ((u >> 16) & 1u)) >> 16;
    return (unsigned short)r;
}

__device__ __forceinline__ float wave_reduce(float p) {
    #pragma unroll
    for (int off = 32; off > 0; off >>= 1)
        p += __shfl_xor(p, off, 64);
    return p;
}

// ---------------- Prologue: ybf = bf16(W + b); reg partials = 0.05*||Y||^2 ----
__global__ __launch_bounds__(256)
void gf_prep_kernel(const float* __restrict__ W, const float* __restrict__ b,
                    unsigned short* __restrict__ ybf, float* __restrict__ regp) {
    __shared__ float s_ws[4];
    const int t = blockIdx.x * 256 + threadIdx.x;
    const int f = t * 4;
    const int dcol = f & (D - 1);
    const float4 wv = *(const float4*)(W + f);
    const float4 bv = *(const float4*)(b + dcol);
    const float y0 = wv.x + bv.x, y1 = wv.y + bv.y, y2 = wv.z + bv.z, y3 = wv.w + bv.w;

    ushort4 o;
    o.x = f32_to_bf16(y0); o.y = f32_to_bf16(y1);
    o.z = f32_to_bf16(y2); o.w = f32_to_bf16(y3);
    *(ushort4*)(ybf + f) = o;

    float s = y0*y0 + y1*y1 + y2*y2 + y3*y3;
    s = wave_reduce(s);
    const int lane = threadIdx.x & 63, w = threadIdx.x >> 6;
    if (lane == 0) s_ws[w] = s;
    __syncthreads();
    if (threadIdx.x == 0)
        regp[blockIdx.x] = 0.05f * (s_ws[0] + s_ws[1] + s_ws[2] + s_ws[3]);
}

// ---------------- Main: dense SDDMM + masked loss, coalesced A -------------
// Grid 64x64; block tile 128(i) x 128(j); 4 waves, wave w owns i-rows
// [i0, i0+32). Two passes of 16 rows: compute 16x128 C via MFMA, spill frags
// to a WAVE-PRIVATE padded LDS stripe, read back as float4 in row-major order
// matched to per-lane float4 A loads (1 KB / wave-instr, 8 independent loads
// per lane -> deep MLP). No __syncthreads in the hot path.
__global__ __launch_bounds__(256, 4)
void gf_sddmm_kernel(const float* __restrict__ A,
                     const unsigned short* __restrict__ ybf,
                     float* __restrict__ partials) {
    __shared__ float s_c[4][16][132];   // 33792 B; stride 132 kills row aliasing
    __shared__ float s_ws[4];

    const int lane = threadIdx.x & 63;
    const int w    = threadIdx.x >> 6;
    const int i0   = blockIdx.x * 128 + w * 32;
    const int j0   = blockIdx.y * 128;
    const int r16  = lane & 15;
    const int quad = lane >> 4;
    const int l32  = lane & 31;
    const int half = lane >> 5;

    // A-operand frags for both 16-row subtiles (K=128 resident in VGPRs)
    short8 afr[2][4];
    #pragma unroll
    for (int s = 0; s < 2; ++s) {
        const unsigned short* yrow = ybf + (size_t)(i0 + s * 16 + r16) * D;
        #pragma unroll
        for (int c = 0; c < 4; ++c)
            afr[s][c] = *(const short8*)(yrow + c * 32 + quad * 8);
    }

    float loss = 0.0f;
    #pragma unroll
    for (int s = 0; s < 2; ++s) {
        // ---- compute 16x128 C stripe, spill frags to wave-private LDS ----
        #pragma unroll
        for (int jj = 0; jj < 8; ++jj) {
            const int jbase = j0 + jj * 16;
            short8 bfr[4];
            const unsigned short* yrow = ybf + (size_t)(jbase + r16) * D;
            #pragma unroll
            for (int c = 0; c < 4; ++c)
                bfr[c] = *(const short8*)(yrow + c * 32 + quad * 8);
            float4v acc = {0.f, 0.f, 0.f, 0.f};
            #pragma unroll
            for (int c = 0; c < 4; ++c)
                acc = __builtin_amdgcn_mfma_f32_16x16x32_bf16(afr[s][c], bfr[c], acc, 0, 0, 0);
            // C/D layout: col = lane&15, row(sub) = quad*4 + r
            #pragma unroll
            for (int r = 0; r < 4; ++r)
                s_c[w][quad * 4 + r][jj * 16 + r16] = acc[r];
        }
        // ---- read back row-major float4 + coalesced float4 A, compare ----
        #pragma unroll
        for (int t = 0; t < 8; ++t) {
            const int m = 2 * t + half;                 // row within the 16
            const float4 cv = *(const float4*)&s_c[w][m][l32 * 4];
            const float4 av = *(const float4*)(A + (size_t)(i0 + s * 16 + m) * N
                                                 + j0 + l32 * 4);
            float d;
            d = av.x - cv.x; loss += (av.x > 0.0f) ? d * d : 0.0f;
            d = av.y - cv.y; loss += (av.y > 0.0f) ? d * d : 0.0f;
            d = av.z - cv.z; loss += (av.z > 0.0f) ? d * d : 0.0f;
            d = av.w - cv.w; loss += (av.w > 0.0f) ? d * d : 0.0f;
        }
    }

    loss = wave_reduce(loss);
    if (lane == 0) s_ws[w] = loss;
    __syncthreads();
    if (threadIdx.x == 0)
        partials[blockIdx.y * gridDim.x + blockIdx.x] =
            0.5f * (s_ws[0] + s_ws[1] + s_ws[2] + s_ws[3]);
}

// ---------------- Final reduce: sum 4096 main + 1024 reg partials ----------
__global__ __launch_bounds__(256)
void gf_reduce_kernel(const float* __restrict__ parts, float* __restrict__ out) {
    __shared__ float s_ws[4];
    const int lane = threadIdx.x & 63, w = threadIdx.x >> 6;
    float s = 0.0f;
    for (int i = threadIdx.x; i < 4096 + 1024; i += 256) s += parts[i];
    s = wave_reduce(s);
    if (lane == 0) s_ws[w] = s;
    __syncthreads();
    if (threadIdx.x == 0) out[0] = s_ws[0] + s_ws[1] + s_ws[2] + s_ws[3];
}

extern "C" void kernel_launch(void* const* d_in, const int* in_sizes, int n_in,
                              void* d_out, int out_size, void* d_ws, size_t ws_size,
                              hipStream_t stream) {
    const float* A = (const float*)d_in[0];
    const float* W = (const float*)d_in[1];
    const float* b = (const float*)d_in[2];
    float* out = (float*)d_out;

    float* parts = (float*)d_ws;                                  // [0,5120) partials
    unsigned short* ybf = (unsigned short*)((float*)d_ws + 8192); // 2 MB bf16 Y

    gf_prep_kernel<<<dim3(N * D / 1024), dim3(256), 0, stream>>>(W, b, ybf, parts + 4096);
    gf_sddmm_kernel<<<dim3(64, 64), dim3(256), 0, stream>>>(A, ybf, parts);
    gf_reduce_kernel<<<dim3(1), dim3(256), 0, stream>>>(parts, out);
}

// Round 6
// 418.660 us; speedup vs baseline: 1.0697x; 1.0697x over previous
//
#include <hip/hip_runtime.h>

#define N 8192
#define D 128

typedef __attribute__((ext_vector_type(8))) short short8;   // 8 bf16 = 4 VGPRs
typedef __attribute__((ext_vector_type(4))) float float4v;  // MFMA C/D

__device__ __forceinline__ unsigned short f32_to_bf16(float f) {
    unsigned int u = __float_as_uint(f);
    unsigned int r = (u + 0x7fffu + ((u >> 16) & 1u)) >> 16;
    return (unsigned short)r;
}

__device__ __forceinline__ float wave_reduce(float p) {
    #pragma unroll
    for (int off = 32; off > 0; off >>= 1)
        p += __shfl_xor(p, off, 64);
    return p;
}

// ---------------- Prologue: ybf = bf16(W + b); reg partials = 0.05*||Y||^2 ----
__global__ __launch_bounds__(256)
void gf_prep_kernel(const float* __restrict__ W, const float* __restrict__ b,
                    unsigned short* __restrict__ ybf, float* __restrict__ regp) {
    __shared__ float s_ws[4];
    const int t = blockIdx.x * 256 + threadIdx.x;
    const int f = t * 4;
    const int dcol = f & (D - 1);
    const float4 wv = *(const float4*)(W + f);
    const float4 bv = *(const float4*)(b + dcol);
    const float y0 = wv.x + bv.x, y1 = wv.y + bv.y, y2 = wv.z + bv.z, y3 = wv.w + bv.w;

    ushort4 o;
    o.x = f32_to_bf16(y0); o.y = f32_to_bf16(y1);
    o.z = f32_to_bf16(y2); o.w = f32_to_bf16(y3);
    *(ushort4*)(ybf + f) = o;

    float s = y0*y0 + y1*y1 + y2*y2 + y3*y3;
    s = wave_reduce(s);
    const int lane = threadIdx.x & 63, w = threadIdx.x >> 6;
    if (lane == 0) s_ws[w] = s;
    __syncthreads();
    if (threadIdx.x == 0)
        regp[blockIdx.x] = 0.05f * (s_ws[0] + s_ws[1] + s_ws[2] + s_ws[3]);
}

// ---------------- Main: dense SDDMM + masked loss ---------------------------
// GRID TRANSPOSED: blockIdx.x = j-tile (fastest) so concurrently-resident
// blocks spread their A addresses across ALL columns -> all HBM channels /
// L3 slices, instead of hammering the 2 channels a fixed 512B column-slab
// maps to (addr = row*32KB + col*4; 32KB stride aliases the interleave).
// Per s-pass: issue all 8 A float4 loads FIRST (8 KB/wave in flight), hide
// their latency under the MFMA phase + wave-private LDS roundtrip, consume.
__global__ __launch_bounds__(256, 4)
void gf_sddmm_kernel(const float* __restrict__ A,
                     const unsigned short* __restrict__ ybf,
                     float* __restrict__ partials) {
    __shared__ float s_c[4][16][132];   // 33792 B; wave-private stripes
    __shared__ float s_ws[4];

    const int lane = threadIdx.x & 63;
    const int w    = threadIdx.x >> 6;
    const int j0   = blockIdx.x * 128;              // fastest dim = columns
    const int i0   = blockIdx.y * 128 + w * 32;
    const int r16  = lane & 15;
    const int quad = lane >> 4;
    const int l32  = lane & 31;
    const int half = lane >> 5;

    // A-operand frags for both 16-row subtiles (K=128 resident in VGPRs)
    short8 afr[2][4];
    #pragma unroll
    for (int s = 0; s < 2; ++s) {
        const unsigned short* yrow = ybf + (size_t)(i0 + s * 16 + r16) * D;
        #pragma unroll
        for (int c = 0; c < 4; ++c)
            afr[s][c] = *(const short8*)(yrow + c * 32 + quad * 8);
    }

    float loss = 0.0f;
    #pragma unroll
    for (int s = 0; s < 2; ++s) {
        // ---- prefetch this pass's A tile: 8 independent float4 loads ----
        float4 av[8];
        #pragma unroll
        for (int t = 0; t < 8; ++t) {
            const int m = 2 * t + half;
            av[t] = *(const float4*)(A + (size_t)(i0 + s * 16 + m) * N + j0 + l32 * 4);
        }
        // ---- compute 16x128 C stripe, spill frags to wave-private LDS ----
        #pragma unroll
        for (int jj = 0; jj < 8; ++jj) {
            const int jbase = j0 + jj * 16;
            short8 bfr[4];
            const unsigned short* yrow = ybf + (size_t)(jbase + r16) * D;
            #pragma unroll
            for (int c = 0; c < 4; ++c)
                bfr[c] = *(const short8*)(yrow + c * 32 + quad * 8);
            float4v acc = {0.f, 0.f, 0.f, 0.f};
            #pragma unroll
            for (int c = 0; c < 4; ++c)
                acc = __builtin_amdgcn_mfma_f32_16x16x32_bf16(afr[s][c], bfr[c], acc, 0, 0, 0);
            // C/D layout: col = lane&15, row(sub) = quad*4 + r
            #pragma unroll
            for (int r = 0; r < 4; ++r)
                s_c[w][quad * 4 + r][jj * 16 + r16] = acc[r];
        }
        // ---- read back row-major float4, compare against prefetched A ----
        #pragma unroll
        for (int t = 0; t < 8; ++t) {
            const int m = 2 * t + half;
            const float4 cv = *(const float4*)&s_c[w][m][l32 * 4];
            float d;
            d = av[t].x - cv.x; loss += (av[t].x > 0.0f) ? d * d : 0.0f;
            d = av[t].y - cv.y; loss += (av[t].y > 0.0f) ? d * d : 0.0f;
            d = av[t].z - cv.z; loss += (av[t].z > 0.0f) ? d * d : 0.0f;
            d = av[t].w - cv.w; loss += (av[t].w > 0.0f) ? d * d : 0.0f;
        }
    }

    loss = wave_reduce(loss);
    if (lane == 0) s_ws[w] = loss;
    __syncthreads();
    if (threadIdx.x == 0)
        partials[blockIdx.y * gridDim.x + blockIdx.x] =
            0.5f * (s_ws[0] + s_ws[1] + s_ws[2] + s_ws[3]);
}

// ---------------- Final reduce: sum 4096 main + 1024 reg partials ----------
__global__ __launch_bounds__(256)
void gf_reduce_kernel(const float* __restrict__ parts, float* __restrict__ out) {
    __shared__ float s_ws[4];
    const int lane = threadIdx.x & 63, w = threadIdx.x >> 6;
    float s = 0.0f;
    for (int i = threadIdx.x; i < 4096 + 1024; i += 256) s += parts[i];
    s = wave_reduce(s);
    if (lane == 0) s_ws[w] = s;
    __syncthreads();
    if (threadIdx.x == 0) out[0] = s_ws[0] + s_ws[1] + s_ws[2] + s_ws[3];
}

extern "C" void kernel_launch(void* const* d_in, const int* in_sizes, int n_in,
                              void* d_out, int out_size, void* d_ws, size_t ws_size,
                              hipStream_t stream) {
    const float* A = (const float*)d_in[0];
    const float* W = (const float*)d_in[1];
    const float* b = (const float*)d_in[2];
    float* out = (float*)d_out;

    float* parts = (float*)d_ws;                                  // [0,5120) partials
    unsigned short* ybf = (unsigned short*)((float*)d_ws + 8192); // 2 MB bf16 Y

    gf_prep_kernel<<<dim3(N * D / 1024), dim3(256), 0, stream>>>(W, b, ybf, parts + 4096);
    gf_sddmm_kernel<<<dim3(64, 64), dim3(256), 0, stream>>>(A, ybf, parts);
    gf_reduce_kernel<<<dim3(1), dim3(256), 0, stream>>>(parts, out);
}